// Round 2
// baseline (292.724 us; speedup 1.0000x reference)
//
#include <hip/hip_runtime.h>

#define NN 8192
#define FF 256
#define MM 128
#define KC 32
#define HSLOTS 262144   // power of 2, 2x edge count

// ws layout (bytes):
// [0,256): accumulators  acc[0]=kl, acc[1]=edge_sum, acc[2]=softplus_sum
// [256, 256+4MB): z [NN][MM] fp32
// [256+4MB, +1MB): dedup hash set (u32 keys, 0 = empty)
#define ACC_OFF   0
#define Z_OFF     256
#define Z_BYTES   (NN * MM * 4)
#define HASH_OFF  (Z_OFF + Z_BYTES)

__device__ __forceinline__ float softplus_f(float v) {
    // stable: max(v,0) + log1p(exp(-|v|)); fast intrinsics fine at 2% tol
    return fmaxf(v, 0.f) + __logf(1.f + __expf(-fabsf(v)));
}

__device__ __forceinline__ float wave_reduce(float v) {
    #pragma unroll
    for (int off = 32; off > 0; off >>= 1) v += __shfl_down(v, off);
    return v;
}

// ---------------- encoder: mu/logstd GEMMs + rsample + KL ----------------
__global__ __launch_bounds__(256)
void encoder_kernel(const float* __restrict__ x, const float* __restrict__ eps,
                    const float* __restrict__ Wmu, const float* __restrict__ bmu,
                    const float* __restrict__ Wsg, const float* __restrict__ bsg,
                    float* __restrict__ z, float* __restrict__ acc) {
    __shared__ float xs[16 * FF];   // 16 rows of x, row-major, 16 KB
    __shared__ float red[4];
    const int tid = threadIdx.x;
    const int n0 = blockIdx.x * 16;

    {   // coalesced float4 stage of 16 x-rows
        const float4* xg = (const float4*)(x + (size_t)n0 * FF);
        float4* xsv = (float4*)xs;
        #pragma unroll
        for (int it = 0; it < 4; ++it) xsv[tid + it * 256] = xg[tid + it * 256];
    }
    __syncthreads();

    const int tm = tid & (MM - 1);   // latent column
    const int tg = tid >> 7;         // row group: rows tg*8 .. tg*8+7

    float amu[8], asg[8];
    #pragma unroll
    for (int r = 0; r < 8; ++r) { amu[r] = 0.f; asg[r] = 0.f; }

    #pragma unroll 2
    for (int f4 = 0; f4 < FF / 4; ++f4) {
        float4 xr[8];
        #pragma unroll
        for (int r = 0; r < 8; ++r)
            xr[r] = *(const float4*)&xs[(tg * 8 + r) * FF + f4 * 4];
        #pragma unroll
        for (int u = 0; u < 4; ++u) {
            const int f = f4 * 4 + u;
            const float wm = Wmu[f * MM + tm];
            const float wsv = Wsg[f * MM + tm];
            #pragma unroll
            for (int r = 0; r < 8; ++r) {
                const float xv = ((const float*)&xr[r])[u];
                amu[r] = fmaf(xv, wm, amu[r]);
                asg[r] = fmaf(xv, wsv, asg[r]);
            }
        }
    }

    const float bm = bmu[tm], bs = bsg[tm];
    float klp = 0.f;
    #pragma unroll
    for (int r = 0; r < 8; ++r) {
        const int n = n0 + tg * 8 + r;
        const float mu = amu[r] + bm;
        const float ls = asg[r] + bs;
        const float sg = __expf(ls);
        const float zz = fmaf(sg, eps[(size_t)n * MM + tm], mu);
        z[(size_t)n * MM + tm] = zz;
        klp += 0.5f * (sg * sg + mu * mu - 1.f) - ls;
    }

    klp = wave_reduce(klp);
    if ((tid & 63) == 0) red[tid >> 6] = klp;
    __syncthreads();
    if (tid == 0) atomicAdd(acc + 0, red[0] + red[1] + red[2] + red[3]);
}

// ---------------- edges: dedup via hash set, sum s_ij over unique pairs ---
// edge_index is int32 on device (harness converts integer inputs to int).
__global__ __launch_bounds__(256)
void edge_kernel(const int* __restrict__ ei, int E,
                 const float* __restrict__ z, unsigned int* __restrict__ ht,
                 float* __restrict__ acc) {
    const int e = blockIdx.x * 256 + threadIdx.x;
    float contrib = 0.f;
    if (e < E) {
        const int i = ei[e];
        const int j = ei[E + e];
        if (i != j) {  // diagonal excluded by triu(k=1)
            const int a = min(i, j), b = max(i, j);
            const unsigned int key = (unsigned int)a * NN + b;  // >=1, <2^26
            unsigned int slot = (key * 2654435761u) & (HSLOTS - 1);
            bool first = false;
            for (;;) {
                const unsigned int old = atomicCAS(&ht[slot], 0u, key);
                if (old == 0u) { first = true; break; }   // we inserted it
                if (old == key) break;                    // duplicate pair
                slot = (slot + 1) & (HSLOTS - 1);         // linear probe
            }
            if (first) {
                const float4* za = (const float4*)(z + (size_t)a * MM);
                const float4* zb = (const float4*)(z + (size_t)b * MM);
                float s = 0.f;
                #pragma unroll
                for (int q = 0; q < MM / 4; ++q) {
                    const float4 va = za[q], vb = zb[q];
                    s += va.x * vb.x + va.y * vb.y + va.z * vb.z + va.w * vb.w;
                }
                contrib = s;
            }
        }
    }
    contrib = wave_reduce(contrib);
    if ((threadIdx.x & 63) == 0) atomicAdd(acc + 1, contrib);
}

// ---------------- dominant: upper-tri tiles of z@z^T, fused softplus sum --
__global__ __launch_bounds__(256)
void tile_kernel(const float* __restrict__ z, float* __restrict__ acc) {
    const int bi = blockIdx.y, bj = blockIdx.x;
    if (bj < bi) return;   // upper triangle of 128x128 tiles only

    __shared__ float zr[KC][128];   // transposed: [k][row], 16 KB
    __shared__ float zc[KC][128];   // transposed: [k][col], 16 KB
    __shared__ float red[4];

    const int tid = threadIdx.x;
    const int wid = tid >> 6, lane = tid & 63;
    // 8x8 wave sub-tiling: wave covers 8 col-groups x 8 row-groups ->
    // per LDS instr: 8 distinct 16B chunks (2-way bank alias = free)
    const int tx = (lane & 7) + (wid & 1) * 8;         // 0..15 col group
    const int ty = (lane >> 3) + ((wid >> 1) & 1) * 8; // 0..15 row group
    const int r0 = ty * 8, c0 = tx * 8;

    float s[8][8];
    #pragma unroll
    for (int i = 0; i < 8; ++i)
        #pragma unroll
        for (int j = 0; j < 8; ++j) s[i][j] = 0.f;

    const float* zrow = z + (size_t)bi * 128 * MM;
    const float* zcol = z + (size_t)bj * 128 * MM;
    const int srow = tid >> 1;
    const int qb = (tid & 1) * 4;

    for (int kc = 0; kc < MM; kc += KC) {
        const float4* gr = (const float4*)(zrow + (size_t)srow * MM + kc);
        const float4* gc = (const float4*)(zcol + (size_t)srow * MM + kc);
        #pragma unroll
        for (int u = 0; u < 4; ++u) {
            const float4 v = gr[qb + u];
            const float4 w = gc[qb + u];
            const int k = (qb + u) * 4;
            zr[k + 0][srow] = v.x; zr[k + 1][srow] = v.y;
            zr[k + 2][srow] = v.z; zr[k + 3][srow] = v.w;
            zc[k + 0][srow] = w.x; zc[k + 1][srow] = w.y;
            zc[k + 2][srow] = w.z; zc[k + 3][srow] = w.w;
        }
        __syncthreads();
        #pragma unroll 4
        for (int k = 0; k < KC; ++k) {
            const float4 a0 = *(const float4*)&zr[k][r0];
            const float4 a1 = *(const float4*)&zr[k][r0 + 4];
            const float4 b0 = *(const float4*)&zc[k][c0];
            const float4 b1 = *(const float4*)&zc[k][c0 + 4];
            const float a[8] = {a0.x, a0.y, a0.z, a0.w, a1.x, a1.y, a1.z, a1.w};
            const float b[8] = {b0.x, b0.y, b0.z, b0.w, b1.x, b1.y, b1.z, b1.w};
            #pragma unroll
            for (int i = 0; i < 8; ++i)
                #pragma unroll
                for (int j = 0; j < 8; ++j)
                    s[i][j] = fmaf(a[i], b[j], s[i][j]);
        }
        __syncthreads();
    }

    float tsum = 0.f;
    const int gi0 = bi * 128 + r0;
    const int gj0 = bj * 128 + c0;
    if (bi != bj) {
        #pragma unroll
        for (int i = 0; i < 8; ++i)
            #pragma unroll
            for (int j = 0; j < 8; ++j) tsum += softplus_f(s[i][j]);
    } else {
        #pragma unroll
        for (int i = 0; i < 8; ++i)
            #pragma unroll
            for (int j = 0; j < 8; ++j)
                if (gj0 + j > gi0 + i) tsum += softplus_f(s[i][j]);
    }

    tsum = wave_reduce(tsum);
    if (lane == 0) red[wid] = tsum;
    __syncthreads();
    if (tid == 0) atomicAdd(acc + 2, red[0] + red[1] + red[2] + red[3]);
}

// ---------------- final combine ----------------
__global__ void combine_kernel(const float* __restrict__ acc,
                               float* __restrict__ out) {
    out[0] = acc[2] - acc[1] + 0.001f * acc[0];
}

extern "C" void kernel_launch(void* const* d_in, const int* in_sizes, int n_in,
                              void* d_out, int out_size, void* d_ws, size_t ws_size,
                              hipStream_t stream) {
    const float* x   = (const float*)d_in[0];
    const int* ei    = (const int*)d_in[1];     // int32 on device
    const float* eps = (const float*)d_in[2];
    const float* Wmu = (const float*)d_in[3];
    const float* bmu = (const float*)d_in[4];
    const float* Wsg = (const float*)d_in[5];
    const float* bsg = (const float*)d_in[6];
    float* out = (float*)d_out;
    char* ws = (char*)d_ws;

    float* acc = (float*)(ws + ACC_OFF);
    float* z = (float*)(ws + Z_OFF);
    unsigned int* ht = (unsigned int*)(ws + HASH_OFF);
    const int E = in_sizes[1] / 2;

    hipMemsetAsync(acc, 0, 256, stream);
    hipMemsetAsync(ht, 0, (size_t)HSLOTS * 4, stream);

    encoder_kernel<<<NN / 16, 256, 0, stream>>>(x, eps, Wmu, bmu, Wsg, bsg, z, acc);
    edge_kernel<<<(E + 255) / 256, 256, 0, stream>>>(ei, E, z, ht, acc);
    dim3 grid(NN / 128, NN / 128);
    tile_kernel<<<grid, 256, 0, stream>>>(z, acc);
    combine_kernel<<<1, 1, 0, stream>>>(acc, out);
}

// Round 3
// 166.044 us; speedup vs baseline: 1.7629x; 1.7629x over previous
//
#include <hip/hip_runtime.h>

#define NN 8192
#define FF 256
#define MM 128
#define HSLOTS 262144   // power of 2, 2x edge count

typedef __attribute__((ext_vector_type(8))) short bf16x8;
typedef __attribute__((ext_vector_type(4))) float f32x4;

// ws layout (bytes):
// [0, 16K): partial sums, 3 arrays x 64 slots, each slot 16 floats (64B) apart
//           arr0=kl, arr1=edge_sum, arr2=softplus_sum  (float offsets below)
// [16K, 16K+2MB): z bf16 [NN][MM]
// [16K+2MB, +1MB): dedup hash set (u32 keys, 0 = empty)
#define P_KL    0
#define P_EDGE  (64 * 16)
#define P_SP    (128 * 16)
#define Z_OFF   16384
#define Z_BYTES (NN * MM * 2)
#define HASH_OFF (Z_OFF + Z_BYTES)

__device__ __forceinline__ float softplus_f(float v) {
    return fmaxf(v, 0.f) + __logf(1.f + __expf(-fabsf(v)));
}
__device__ __forceinline__ float wave_reduce(float v) {
    #pragma unroll
    for (int off = 32; off > 0; off >>= 1) v += __shfl_down(v, off);
    return v;
}
__device__ __forceinline__ unsigned short f2bf(float f) {
    unsigned int u = __float_as_uint(f);
    u += 0x7fffu + ((u >> 16) & 1u);   // round to nearest even
    return (unsigned short)(u >> 16);
}

// ---------------- encoder: mu/logstd GEMMs + rsample + KL, z -> bf16 ------
__global__ __launch_bounds__(256)
void encoder_kernel(const float* __restrict__ x, const float* __restrict__ eps,
                    const float* __restrict__ Wmu, const float* __restrict__ bmu,
                    const float* __restrict__ Wsg, const float* __restrict__ bsg,
                    unsigned short* __restrict__ zb, float* __restrict__ part) {
    __shared__ float xs[16 * FF];
    __shared__ float red[4];
    const int tid = threadIdx.x;
    const int n0 = blockIdx.x * 16;

    {
        const float4* xg = (const float4*)(x + (size_t)n0 * FF);
        float4* xsv = (float4*)xs;
        #pragma unroll
        for (int it = 0; it < 4; ++it) xsv[tid + it * 256] = xg[tid + it * 256];
    }
    __syncthreads();

    const int tm = tid & (MM - 1);
    const int tg = tid >> 7;

    float amu[8], asg[8];
    #pragma unroll
    for (int r = 0; r < 8; ++r) { amu[r] = 0.f; asg[r] = 0.f; }

    #pragma unroll 2
    for (int f4 = 0; f4 < FF / 4; ++f4) {
        float4 xr[8];
        #pragma unroll
        for (int r = 0; r < 8; ++r)
            xr[r] = *(const float4*)&xs[(tg * 8 + r) * FF + f4 * 4];
        #pragma unroll
        for (int u = 0; u < 4; ++u) {
            const int f = f4 * 4 + u;
            const float wm = Wmu[f * MM + tm];
            const float wsv = Wsg[f * MM + tm];
            #pragma unroll
            for (int r = 0; r < 8; ++r) {
                const float xv = ((const float*)&xr[r])[u];
                amu[r] = fmaf(xv, wm, amu[r]);
                asg[r] = fmaf(xv, wsv, asg[r]);
            }
        }
    }

    const float bm = bmu[tm], bs = bsg[tm];
    float klp = 0.f;
    #pragma unroll
    for (int r = 0; r < 8; ++r) {
        const int n = n0 + tg * 8 + r;
        const float mu = amu[r] + bm;
        const float ls = asg[r] + bs;
        const float sg = __expf(ls);
        const float zz = fmaf(sg, eps[(size_t)n * MM + tm], mu);
        zb[(size_t)n * MM + tm] = f2bf(zz);
        klp += 0.5f * (sg * sg + mu * mu - 1.f) - ls;
    }

    klp = wave_reduce(klp);
    if ((tid & 63) == 0) red[tid >> 6] = klp;
    __syncthreads();
    if (tid == 0)
        atomicAdd(&part[P_KL + (blockIdx.x & 63) * 16],
                  red[0] + red[1] + red[2] + red[3]);
}

// ---------------- edges: dedup hash, sum s_ij over unique pairs (bf16 z) --
__device__ __forceinline__ float dotpair(unsigned int a, unsigned int b) {
    const float al = __uint_as_float(a << 16);
    const float ah = __uint_as_float(a & 0xffff0000u);
    const float bl = __uint_as_float(b << 16);
    const float bh = __uint_as_float(b & 0xffff0000u);
    return fmaf(al, bl, ah * bh);
}

__global__ __launch_bounds__(256)
void edge_kernel(const int* __restrict__ ei, int E,
                 const unsigned short* __restrict__ zb,
                 unsigned int* __restrict__ ht, float* __restrict__ part) {
    const int e = blockIdx.x * 256 + threadIdx.x;
    float contrib = 0.f;
    if (e < E) {
        const int i = ei[e];
        const int j = ei[E + e];
        if (i != j) {
            const int a = min(i, j), b = max(i, j);
            const unsigned int key = (unsigned int)a * NN + b;  // >=1, <2^26
            unsigned int slot = (key * 2654435761u) & (HSLOTS - 1);
            bool first = false;
            for (;;) {
                const unsigned int old = atomicCAS(&ht[slot], 0u, key);
                if (old == 0u) { first = true; break; }
                if (old == key) break;
                slot = (slot + 1) & (HSLOTS - 1);
            }
            if (first) {
                const uint4* za = (const uint4*)(zb + (size_t)a * MM);
                const uint4* zc = (const uint4*)(zb + (size_t)b * MM);
                float s = 0.f;
                #pragma unroll
                for (int q = 0; q < MM / 8; ++q) {   // 16 x 16B chunks
                    const uint4 ua = za[q], ub = zc[q];
                    s += dotpair(ua.x, ub.x) + dotpair(ua.y, ub.y)
                       + dotpair(ua.z, ub.z) + dotpair(ua.w, ub.w);
                }
                contrib = s;
            }
        }
    }
    contrib = wave_reduce(contrib);
    if ((threadIdx.x & 63) == 0)
        atomicAdd(&part[P_EDGE + (blockIdx.x & 63) * 16], contrib);
}

// ---------------- dominant: MFMA bf16 upper-tri z@z^T + fused softplus ----
// LDS: two tiles [128 rows][64 bf16 + 8 pad] = 2 x 18KB, staged in 2 K-halves.
#define PITCH_I4 9    // int4 per LDS row (8 data + 1 pad = 144B, bank-balanced)
#define PITCH_S  72   // shorts per LDS row

__global__ __launch_bounds__(256)
void tile_kernel(const unsigned short* __restrict__ zb, float* __restrict__ part) {
    const int bi = blockIdx.y, bj = blockIdx.x;
    if (bj < bi) return;   // upper triangle of 128x128 tiles

    __shared__ int4 lds[2 * 128 * PITCH_I4];
    __shared__ float red[4];
    int4* la = lds;
    int4* lb = lds + 128 * PITCH_I4;

    const int tid = threadIdx.x;
    const int wid = tid >> 6, lane = tid & 63;
    const int wm = wid >> 1, wn = wid & 1;    // 2x2 waves over 128x128
    const int l15 = lane & 15, quad = lane >> 4;

    const int4* ga = (const int4*)(zb + (size_t)bi * 128 * MM);
    const int4* gb = (const int4*)(zb + (size_t)bj * 128 * MM);

    f32x4 zero4 = {0.f, 0.f, 0.f, 0.f};
    f32x4 acc[4][4];
    #pragma unroll
    for (int i = 0; i < 4; ++i)
        #pragma unroll
        for (int j = 0; j < 4; ++j) acc[i][j] = zero4;

    const short* sa = (const short*)la;
    const short* sb = (const short*)lb;

    #pragma unroll
    for (int kc = 0; kc < 2; ++kc) {       // K halves: 64 each
        if (kc) __syncthreads();           // LDS reuse barrier
        #pragma unroll
        for (int i = 0; i < 4; ++i) {      // stage 2 x 16KB (half-rows of z)
            const int c = tid + i * 256;   // 0..1023
            const int row = c >> 3, ch = c & 7;
            la[row * PITCH_I4 + ch] = ga[row * 16 + kc * 8 + ch];
            lb[row * PITCH_I4 + ch] = gb[row * 16 + kc * 8 + ch];
        }
        __syncthreads();
        #pragma unroll
        for (int ks = 0; ks < 2; ++ks) {   // two k=32 MFMA steps per half
            bf16x8 af[4], bfr[4];
            #pragma unroll
            for (int t = 0; t < 4; ++t) {
                const int ar = wm * 64 + t * 16 + l15;
                af[t] = *(const bf16x8*)&sa[ar * PITCH_S + ks * 32 + quad * 8];
                const int br = wn * 64 + t * 16 + l15;
                bfr[t] = *(const bf16x8*)&sb[br * PITCH_S + ks * 32 + quad * 8];
            }
            #pragma unroll
            for (int i = 0; i < 4; ++i)
                #pragma unroll
                for (int j = 0; j < 4; ++j)
                    acc[i][j] = __builtin_amdgcn_mfma_f32_16x16x32_bf16(
                        af[i], bfr[j], acc[i][j], 0, 0, 0);
        }
    }

    // epilogue: softplus over held C fragments; C/D map: col=lane&15,
    // row=(lane>>4)*4+reg  [m89-verified]
    float tsum = 0.f;
    if (bi != bj) {
        #pragma unroll
        for (int i = 0; i < 4; ++i)
            #pragma unroll
            for (int j = 0; j < 4; ++j)
                #pragma unroll
                for (int r = 0; r < 4; ++r) tsum += softplus_f(acc[i][j][r]);
    } else {
        const int rbase = wm * 64 + quad * 4;
        const int cbase = wn * 64 + l15;
        #pragma unroll
        for (int i = 0; i < 4; ++i)
            #pragma unroll
            for (int j = 0; j < 4; ++j)
                #pragma unroll
                for (int r = 0; r < 4; ++r)
                    if (cbase + j * 16 > rbase + i * 16 + r)
                        tsum += softplus_f(acc[i][j][r]);
    }

    tsum = wave_reduce(tsum);
    if (lane == 0) red[wid] = tsum;
    __syncthreads();
    if (tid == 0)
        atomicAdd(&part[P_SP + ((bi * 64 + bj) & 63) * 16],
                  red[0] + red[1] + red[2] + red[3]);
}

// ---------------- final combine: sum 3 x 64 partial slots ----------------
__global__ void combine_kernel(const float* __restrict__ part,
                               float* __restrict__ out) {
    const int t = threadIdx.x;   // 64 threads
    float v = part[P_SP + t * 16] - part[P_EDGE + t * 16]
            + 0.001f * part[P_KL + t * 16];
    v = wave_reduce(v);
    if (t == 0) out[0] = v;
}

extern "C" void kernel_launch(void* const* d_in, const int* in_sizes, int n_in,
                              void* d_out, int out_size, void* d_ws, size_t ws_size,
                              hipStream_t stream) {
    const float* x   = (const float*)d_in[0];
    const int* ei    = (const int*)d_in[1];     // int32 on device
    const float* eps = (const float*)d_in[2];
    const float* Wmu = (const float*)d_in[3];
    const float* bmu = (const float*)d_in[4];
    const float* Wsg = (const float*)d_in[5];
    const float* bsg = (const float*)d_in[6];
    float* out = (float*)d_out;
    char* ws = (char*)d_ws;

    float* part = (float*)ws;
    unsigned short* zb = (unsigned short*)(ws + Z_OFF);
    unsigned int* ht = (unsigned int*)(ws + HASH_OFF);
    const int E = in_sizes[1] / 2;

    hipMemsetAsync(part, 0, 16384, stream);
    hipMemsetAsync(ht, 0, (size_t)HSLOTS * 4, stream);

    encoder_kernel<<<NN / 16, 256, 0, stream>>>(x, eps, Wmu, bmu, Wsg, bsg, zb, part);
    edge_kernel<<<(E + 255) / 256, 256, 0, stream>>>(ei, E, zb, ht, part);
    dim3 grid(NN / 128, NN / 128);
    tile_kernel<<<grid, 256, 0, stream>>>(zb, part);
    combine_kernel<<<1, 64, 0, stream>>>(part, out);
}

// Round 4
// 145.675 us; speedup vs baseline: 2.0094x; 1.1398x over previous
//
#include <hip/hip_runtime.h>

#define NN 8192
#define FF 256
#define MM 128
#define HSLOTS 262144   // power of 2, 2x edge count

typedef __attribute__((ext_vector_type(8))) short bf16x8;
typedef __attribute__((ext_vector_type(4))) float f32x4;

// ws layout (bytes):
// [0, 16K): partial sums, 3 arrays x 64 slots, 64B apart (float offsets below)
// [16K, +2MB): z bf16 [NN][MM]
// [.., +1MB): dedup hash set (u32 keys, 0 = empty)
// [.., +64KB): WmuT bf16 [MM][FF]   (transposed, K contiguous)
// [.., +64KB): WsgT bf16 [MM][FF]
#define P_KL    0
#define P_EDGE  (64 * 16)
#define P_SP    (128 * 16)
#define Z_OFF   16384
#define Z_BYTES (NN * MM * 2)
#define HASH_OFF (Z_OFF + Z_BYTES)
#define WT_OFF  (HASH_OFF + HSLOTS * 4)
#define WT_BYTES (MM * FF * 2)

__device__ __forceinline__ float softplus_f(float v) {
    return fmaxf(v, 0.f) + __logf(1.f + __expf(-fabsf(v)));
}
__device__ __forceinline__ float wave_reduce(float v) {
    #pragma unroll
    for (int off = 32; off > 0; off >>= 1) v += __shfl_down(v, off);
    return v;
}
__device__ __forceinline__ unsigned short f2bf(float f) {
    unsigned int u = __float_as_uint(f);
    u += 0x7fffu + ((u >> 16) & 1u);   // round to nearest even
    return (unsigned short)(u >> 16);
}
__device__ __forceinline__ int4 pack8(float4 a, float4 b) {
    int4 p;
    p.x = (int)f2bf(a.x) | ((int)f2bf(a.y) << 16);
    p.y = (int)f2bf(a.z) | ((int)f2bf(a.w) << 16);
    p.z = (int)f2bf(b.x) | ((int)f2bf(b.y) << 16);
    p.w = (int)f2bf(b.z) | ((int)f2bf(b.w) << 16);
    return p;
}

// -------- prep: W [K][N] fp32 -> WT [N][K] bf16 (write-coalesced) ---------
__global__ __launch_bounds__(256)
void prep_w(const float* __restrict__ Wmu, const float* __restrict__ Wsg,
            unsigned short* __restrict__ WmuT, unsigned short* __restrict__ WsgT) {
    const int t = blockIdx.x * 256 + threadIdx.x;   // 0..32767
    const int n = t >> 8;        // 0..127
    const int f = t & 255;       // 0..255
    WmuT[t] = f2bf(Wmu[f * MM + n]);
    WsgT[t] = f2bf(Wsg[f * MM + n]);
}

// -------- encoder: MFMA bf16 GEMMs (mu & logstd) + rsample + KL ----------
#define EP_I4 9    // int4 per LDS row (8 data + 1 pad = 144B)
#define EP_S  72   // shorts per LDS row

__global__ __launch_bounds__(256)
void encoder_mfma(const float* __restrict__ x, const float* __restrict__ eps,
                  const unsigned short* __restrict__ WmuT,
                  const unsigned short* __restrict__ WsgT,
                  const float* __restrict__ bmu, const float* __restrict__ bsg,
                  unsigned short* __restrict__ zb, float* __restrict__ part) {
    __shared__ int4 ax[32 * EP_I4];    // 4.5 KB: 32 x rows, 64 bf16 k-chunk
    __shared__ int4 bm_[128 * EP_I4];  // 18 KB: WmuT rows, 64 bf16 k-chunk
    __shared__ int4 bs_[128 * EP_I4];  // 18 KB
    __shared__ float red[4];

    const int tid = threadIdx.x;
    const int wid = tid >> 6, lane = tid & 63;
    const int l15 = lane & 15, quad = lane >> 4;
    const int row0 = blockIdx.x * 32;

    f32x4 zero4 = {0.f, 0.f, 0.f, 0.f};
    f32x4 accm[2][2], accl[2][2];
    #pragma unroll
    for (int i = 0; i < 2; ++i)
        #pragma unroll
        for (int j = 0; j < 2; ++j) { accm[i][j] = zero4; accl[i][j] = zero4; }

    const short* sax = (const short*)ax;
    const short* sbm = (const short*)bm_;
    const short* sbs = (const short*)bs_;
    const int4* wtm = (const int4*)WmuT;   // 32 int4 per row of 256 bf16
    const int4* wts = (const int4*)WsgT;

    #pragma unroll
    for (int kc = 0; kc < 4; ++kc) {       // K chunks of 64
        if (kc) __syncthreads();
        {   // stage x rows (fp32 -> bf16): 32 rows x 64 k = 8 floats/thread
            const int r = tid >> 3, c8 = tid & 7;
            const float4* gx = (const float4*)(x + (size_t)(row0 + r) * FF
                                               + kc * 64 + c8 * 8);
            ax[r * EP_I4 + c8] = pack8(gx[0], gx[1]);
        }
        #pragma unroll
        for (int i = 0; i < 4; ++i) {      // stage both W tiles: 128 rows x 8 int4
            const int c = tid + i * 256;
            const int n = c >> 3, ch = c & 7;
            bm_[n * EP_I4 + ch] = wtm[n * 32 + kc * 8 + ch];
            bs_[n * EP_I4 + ch] = wts[n * 32 + kc * 8 + ch];
        }
        __syncthreads();
        #pragma unroll
        for (int ks = 0; ks < 2; ++ks) {   // two k=32 MFMA steps
            bf16x8 a[2], bmf[2], bsf[2];
            #pragma unroll
            for (int t = 0; t < 2; ++t) {
                a[t]   = *(const bf16x8*)&sax[(t * 16 + l15) * EP_S + ks * 32 + quad * 8];
                const int n = wid * 32 + t * 16 + l15;
                bmf[t] = *(const bf16x8*)&sbm[n * EP_S + ks * 32 + quad * 8];
                bsf[t] = *(const bf16x8*)&sbs[n * EP_S + ks * 32 + quad * 8];
            }
            #pragma unroll
            for (int i = 0; i < 2; ++i)
                #pragma unroll
                for (int j = 0; j < 2; ++j) {
                    accm[i][j] = __builtin_amdgcn_mfma_f32_16x16x32_bf16(
                        a[i], bmf[j], accm[i][j], 0, 0, 0);
                    accl[i][j] = __builtin_amdgcn_mfma_f32_16x16x32_bf16(
                        a[i], bsf[j], accl[i][j], 0, 0, 0);
                }
        }
    }

    // epilogue: C map col=lane&15, row=quad*4+reg [m89]
    float klp = 0.f;
    #pragma unroll
    for (int j = 0; j < 2; ++j) {
        const int col = wid * 32 + j * 16 + l15;
        const float bm = bmu[col], bs = bsg[col];
        #pragma unroll
        for (int i = 0; i < 2; ++i)
            #pragma unroll
            for (int r = 0; r < 4; ++r) {
                const int row = row0 + i * 16 + quad * 4 + r;
                const float mu = accm[i][j][r] + bm;
                const float ls = accl[i][j][r] + bs;
                const float sg = __expf(ls);
                const float zz = fmaf(sg, eps[row * MM + col], mu);
                zb[row * MM + col] = f2bf(zz);
                klp += 0.5f * (sg * sg + mu * mu - 1.f) - ls;
            }
    }

    klp = wave_reduce(klp);
    if (lane == 0) red[wid] = klp;
    __syncthreads();
    if (tid == 0)
        atomicAdd(&part[P_KL + (blockIdx.x & 63) * 16],
                  red[0] + red[1] + red[2] + red[3]);
}

// ---------------- edges: dedup hash, sum s_ij over unique pairs (bf16 z) --
__device__ __forceinline__ float dotpair(unsigned int a, unsigned int b) {
    const float al = __uint_as_float(a << 16);
    const float ah = __uint_as_float(a & 0xffff0000u);
    const float bl = __uint_as_float(b << 16);
    const float bh = __uint_as_float(b & 0xffff0000u);
    return fmaf(al, bl, ah * bh);
}

__global__ __launch_bounds__(256)
void edge_kernel(const int* __restrict__ ei, int E,
                 const unsigned short* __restrict__ zb,
                 unsigned int* __restrict__ ht, float* __restrict__ part) {
    const int e = blockIdx.x * 256 + threadIdx.x;
    float contrib = 0.f;
    if (e < E) {
        const int i = ei[e];
        const int j = ei[E + e];
        if (i != j) {
            const int a = min(i, j), b = max(i, j);
            const unsigned int key = (unsigned int)a * NN + b;  // >=1, <2^26
            unsigned int slot = (key * 2654435761u) & (HSLOTS - 1);
            bool first = false;
            for (;;) {
                const unsigned int old = atomicCAS(&ht[slot], 0u, key);
                if (old == 0u) { first = true; break; }
                if (old == key) break;
                slot = (slot + 1) & (HSLOTS - 1);
            }
            if (first) {
                const uint4* za = (const uint4*)(zb + (size_t)a * MM);
                const uint4* zc = (const uint4*)(zb + (size_t)b * MM);
                float s = 0.f;
                #pragma unroll
                for (int q = 0; q < MM / 8; ++q) {
                    const uint4 ua = za[q], ub = zc[q];
                    s += dotpair(ua.x, ub.x) + dotpair(ua.y, ub.y)
                       + dotpair(ua.z, ub.z) + dotpair(ua.w, ub.w);
                }
                contrib = s;
            }
        }
    }
    contrib = wave_reduce(contrib);
    if ((threadIdx.x & 63) == 0)
        atomicAdd(&part[P_EDGE + (blockIdx.x & 63) * 16], contrib);
}

// ---------------- dominant: MFMA bf16 upper-tri z@z^T + fused softplus ----
#define PITCH_I4 9
#define PITCH_S  72

__global__ __launch_bounds__(256)
void tile_kernel(const unsigned short* __restrict__ zb, float* __restrict__ part) {
    const int bi = blockIdx.y, bj = blockIdx.x;
    if (bj < bi) return;   // upper triangle of 128x128 tiles

    __shared__ int4 lds[2 * 128 * PITCH_I4];
    __shared__ float red[4];
    int4* la = lds;
    int4* lb = lds + 128 * PITCH_I4;

    const int tid = threadIdx.x;
    const int wid = tid >> 6, lane = tid & 63;
    const int wm = wid >> 1, wn = wid & 1;
    const int l15 = lane & 15, quad = lane >> 4;

    const int4* ga = (const int4*)(zb + (size_t)bi * 128 * MM);
    const int4* gb = (const int4*)(zb + (size_t)bj * 128 * MM);

    f32x4 zero4 = {0.f, 0.f, 0.f, 0.f};
    f32x4 acc[4][4];
    #pragma unroll
    for (int i = 0; i < 4; ++i)
        #pragma unroll
        for (int j = 0; j < 4; ++j) acc[i][j] = zero4;

    const short* sa = (const short*)la;
    const short* sb = (const short*)lb;

    #pragma unroll
    for (int kc = 0; kc < 2; ++kc) {
        if (kc) __syncthreads();
        #pragma unroll
        for (int i = 0; i < 4; ++i) {
            const int c = tid + i * 256;
            const int row = c >> 3, ch = c & 7;
            la[row * PITCH_I4 + ch] = ga[row * 16 + kc * 8 + ch];
            lb[row * PITCH_I4 + ch] = gb[row * 16 + kc * 8 + ch];
        }
        __syncthreads();
        #pragma unroll
        for (int ks = 0; ks < 2; ++ks) {
            bf16x8 af[4], bfr[4];
            #pragma unroll
            for (int t = 0; t < 4; ++t) {
                const int ar = wm * 64 + t * 16 + l15;
                af[t] = *(const bf16x8*)&sa[ar * PITCH_S + ks * 32 + quad * 8];
                const int br = wn * 64 + t * 16 + l15;
                bfr[t] = *(const bf16x8*)&sb[br * PITCH_S + ks * 32 + quad * 8];
            }
            #pragma unroll
            for (int i = 0; i < 4; ++i)
                #pragma unroll
                for (int j = 0; j < 4; ++j)
                    acc[i][j] = __builtin_amdgcn_mfma_f32_16x16x32_bf16(
                        af[i], bfr[j], acc[i][j], 0, 0, 0);
        }
    }

    float tsum = 0.f;
    if (bi != bj) {
        #pragma unroll
        for (int i = 0; i < 4; ++i)
            #pragma unroll
            for (int j = 0; j < 4; ++j)
                #pragma unroll
                for (int r = 0; r < 4; ++r) tsum += softplus_f(acc[i][j][r]);
    } else {
        const int rbase = wm * 64 + quad * 4;
        const int cbase = wn * 64 + l15;
        #pragma unroll
        for (int i = 0; i < 4; ++i)
            #pragma unroll
            for (int j = 0; j < 4; ++j)
                #pragma unroll
                for (int r = 0; r < 4; ++r)
                    if (cbase + j * 16 > rbase + i * 16 + r)
                        tsum += softplus_f(acc[i][j][r]);
    }

    tsum = wave_reduce(tsum);
    if (lane == 0) red[wid] = tsum;
    __syncthreads();
    if (tid == 0)
        atomicAdd(&part[P_SP + ((bi * 64 + bj) & 63) * 16],
                  red[0] + red[1] + red[2] + red[3]);
}

// ---------------- final combine: sum 3 x 64 partial slots ----------------
__global__ void combine_kernel(const float* __restrict__ part,
                               float* __restrict__ out) {
    const int t = threadIdx.x;   // 64 threads
    float v = part[P_SP + t * 16] - part[P_EDGE + t * 16]
            + 0.001f * part[P_KL + t * 16];
    v = wave_reduce(v);
    if (t == 0) out[0] = v;
}

extern "C" void kernel_launch(void* const* d_in, const int* in_sizes, int n_in,
                              void* d_out, int out_size, void* d_ws, size_t ws_size,
                              hipStream_t stream) {
    const float* x   = (const float*)d_in[0];
    const int* ei    = (const int*)d_in[1];     // int32 on device
    const float* eps = (const float*)d_in[2];
    const float* Wmu = (const float*)d_in[3];
    const float* bmu = (const float*)d_in[4];
    const float* Wsg = (const float*)d_in[5];
    const float* bsg = (const float*)d_in[6];
    float* out = (float*)d_out;
    char* ws = (char*)d_ws;

    float* part = (float*)ws;
    unsigned short* zb = (unsigned short*)(ws + Z_OFF);
    unsigned int* ht = (unsigned int*)(ws + HASH_OFF);
    unsigned short* WmuT = (unsigned short*)(ws + WT_OFF);
    unsigned short* WsgT = (unsigned short*)(ws + WT_OFF + WT_BYTES);
    const int E = in_sizes[1] / 2;

    hipMemsetAsync(part, 0, 16384, stream);
    hipMemsetAsync(ht, 0, (size_t)HSLOTS * 4, stream);

    prep_w<<<128, 256, 0, stream>>>(Wmu, Wsg, WmuT, WsgT);
    encoder_mfma<<<NN / 32, 256, 0, stream>>>(x, eps, WmuT, WsgT, bmu, bsg, zb, part);
    edge_kernel<<<(E + 255) / 256, 256, 0, stream>>>(ei, E, zb, ht, part);
    dim3 grid(NN / 128, NN / 128);
    tile_kernel<<<grid, 256, 0, stream>>>(zb, part);
    combine_kernel<<<1, 64, 0, stream>>>(part, out);
}

// Round 5
// 129.554 us; speedup vs baseline: 2.2595x; 1.1244x over previous
//
#include <hip/hip_runtime.h>

#define NN 8192
#define FF 256
#define MM 128
#define HSLOTS 262144   // power of 2, 2x edge count

typedef __attribute__((ext_vector_type(8))) short bf16x8;
typedef __attribute__((ext_vector_type(4))) float f32x4;

// ws layout (bytes):
// [0, 16K): partial sums, 3 arrays x 64 slots, 64B apart
// [16K, +2MB): z bf16 [NN][MM]
// [.., +1MB): dedup hash set (u32 keys, 0 = empty; zeroed in prep_w)
// [.., +64KB): WmuT bf16 [MM][FF]   (transposed, K contiguous)
// [.., +64KB): WsgT bf16 [MM][FF]
#define P_KL    0
#define P_EDGE  (64 * 16)
#define P_SP    (128 * 16)
#define Z_OFF   16384
#define Z_BYTES (NN * MM * 2)
#define HASH_OFF (Z_OFF + Z_BYTES)
#define WT_OFF  (HASH_OFF + HSLOTS * 4)
#define WT_BYTES (MM * FF * 2)

__device__ __forceinline__ float wave_reduce(float v) {
    #pragma unroll
    for (int off = 32; off > 0; off >>= 1) v += __shfl_down(v, off);
    return v;
}
__device__ __forceinline__ unsigned short f2bf(float f) {
    unsigned int u = __float_as_uint(f);
    u += 0x7fffu + ((u >> 16) & 1u);   // round to nearest even
    return (unsigned short)(u >> 16);
}
__device__ __forceinline__ int4 pack8(float4 a, float4 b) {
    int4 p;
    p.x = (int)f2bf(a.x) | ((int)f2bf(a.y) << 16);
    p.y = (int)f2bf(a.z) | ((int)f2bf(a.w) << 16);
    p.z = (int)f2bf(b.x) | ((int)f2bf(b.y) << 16);
    p.w = (int)f2bf(b.z) | ((int)f2bf(b.w) << 16);
    return p;
}

// ---- prep: W transpose->bf16, zero partials, zero hash table -------------
__global__ __launch_bounds__(256)
void prep_w(const float* __restrict__ Wmu, const float* __restrict__ Wsg,
            unsigned short* __restrict__ WmuT, unsigned short* __restrict__ WsgT,
            float* __restrict__ part, unsigned int* __restrict__ ht) {
    const int t = blockIdx.x * 256 + threadIdx.x;   // 0..32767
    const int n = t >> 8, f = t & 255;
    WmuT[t] = f2bf(Wmu[f * MM + n]);
    WsgT[t] = f2bf(Wsg[f * MM + n]);
    if (t < 4096) part[t] = 0.f;          // 16 KB of partial slots
    uint4 z4 = {0u, 0u, 0u, 0u};
    ((uint4*)ht)[t * 2]     = z4;         // 32768*2 uint4 = 262144 words
    ((uint4*)ht)[t * 2 + 1] = z4;
}

// ---- encoder: MFMA GEMMs, W-fragments direct from global, 1 barrier ------
#define XP_I4 33   // int4 pitch per x row (32 data + 1 pad)
#define XP_S  264

__global__ __launch_bounds__(256)
void encoder_mfma(const float* __restrict__ x, const float* __restrict__ eps,
                  const unsigned short* __restrict__ WmuT,
                  const unsigned short* __restrict__ WsgT,
                  const float* __restrict__ bmu, const float* __restrict__ bsg,
                  unsigned short* __restrict__ zb, float* __restrict__ part) {
    __shared__ int4 ax[16 * XP_I4];   // 8.4 KB: 16 x-rows, K=256 bf16
    __shared__ float red[4];
    const int tid = threadIdx.x;
    const int wid = tid >> 6, lane = tid & 63;
    const int l15 = lane & 15, quad = lane >> 4;
    const int row0 = blockIdx.x * 16;

    {   // stage 16 rows x 256 cols of x as bf16 (coalesced float4 pairs)
        const int r = tid >> 4, ch = tid & 15;
        const float4* g0 = (const float4*)(x + (size_t)(row0 + r) * FF + ch * 8);
        const float4* g1 = (const float4*)(x + (size_t)(row0 + r) * FF + (ch + 16) * 8);
        ax[r * XP_I4 + ch]      = pack8(g0[0], g0[1]);
        ax[r * XP_I4 + ch + 16] = pack8(g1[0], g1[1]);
    }
    __syncthreads();

    const short* sax = (const short*)ax;
    const int4* wtm = (const int4*)WmuT;   // row n = 32 int4 (K=256)
    const int4* wts = (const int4*)WsgT;

    f32x4 zero4 = {0.f, 0.f, 0.f, 0.f};
    f32x4 accm[2], accl[2];
    accm[0] = accm[1] = accl[0] = accl[1] = zero4;

    #pragma unroll
    for (int ks = 0; ks < 8; ++ks) {       // K = 8 x 32
        const bf16x8 a = *(const bf16x8*)&sax[l15 * XP_S + ks * 32 + quad * 8];
        #pragma unroll
        for (int j = 0; j < 2; ++j) {
            const int n = wid * 32 + j * 16 + l15;
            const bf16x8 bmf = *(const bf16x8*)&wtm[n * 32 + ks * 4 + quad];
            const bf16x8 bsf = *(const bf16x8*)&wts[n * 32 + ks * 4 + quad];
            accm[j] = __builtin_amdgcn_mfma_f32_16x16x32_bf16(a, bmf, accm[j], 0, 0, 0);
            accl[j] = __builtin_amdgcn_mfma_f32_16x16x32_bf16(a, bsf, accl[j], 0, 0, 0);
        }
    }

    // epilogue: C map col=lane&15, row=quad*4+reg [m89]
    float klp = 0.f;
    #pragma unroll
    for (int j = 0; j < 2; ++j) {
        const int col = wid * 32 + j * 16 + l15;
        const float bm = bmu[col], bs = bsg[col];
        #pragma unroll
        for (int r = 0; r < 4; ++r) {
            const int row = row0 + quad * 4 + r;
            const float mu = accm[j][r] + bm;
            const float ls = accl[j][r] + bs;
            const float sg = __expf(ls);
            const float zz = fmaf(sg, eps[(size_t)row * MM + col], mu);
            zb[(size_t)row * MM + col] = f2bf(zz);
            klp += 0.5f * (sg * sg + mu * mu - 1.f) - ls;
        }
    }

    klp = wave_reduce(klp);
    if (lane == 0) red[wid] = klp;
    __syncthreads();
    if (tid == 0)
        atomicAdd(&part[P_KL + (blockIdx.x & 63) * 16],
                  red[0] + red[1] + red[2] + red[3]);
}

// ---- edges: dedup hash, sum exact s_ij over unique pairs (bf16 z) --------
__device__ __forceinline__ float dotpair(unsigned int a, unsigned int b) {
    const float al = __uint_as_float(a << 16);
    const float ah = __uint_as_float(a & 0xffff0000u);
    const float bl = __uint_as_float(b << 16);
    const float bh = __uint_as_float(b & 0xffff0000u);
    return fmaf(al, bl, ah * bh);
}

__global__ __launch_bounds__(256)
void edge_kernel(const int* __restrict__ ei, int E,
                 const unsigned short* __restrict__ zb,
                 unsigned int* __restrict__ ht, float* __restrict__ part) {
    const int e = blockIdx.x * 256 + threadIdx.x;
    float contrib = 0.f;
    if (e < E) {
        const int i = ei[e];
        const int j = ei[E + e];
        if (i != j) {
            const int a = min(i, j), b = max(i, j);
            const unsigned int key = (unsigned int)a * NN + b;  // >=1, <2^26
            unsigned int slot = (key * 2654435761u) & (HSLOTS - 1);
            bool first = false;
            for (;;) {
                const unsigned int old = atomicCAS(&ht[slot], 0u, key);
                if (old == 0u) { first = true; break; }
                if (old == key) break;
                slot = (slot + 1) & (HSLOTS - 1);
            }
            if (first) {
                const uint4* za = (const uint4*)(zb + (size_t)a * MM);
                const uint4* zc = (const uint4*)(zb + (size_t)b * MM);
                float s = 0.f;
                #pragma unroll
                for (int q = 0; q < MM / 8; ++q) {
                    const uint4 ua = za[q], ub = zc[q];
                    s += dotpair(ua.x, ub.x) + dotpair(ua.y, ub.y)
                       + dotpair(ua.z, ub.z) + dotpair(ua.w, ub.w);
                }
                contrib = s;
            }
        }
    }
    contrib = wave_reduce(contrib);
    if ((threadIdx.x & 63) == 0)
        atomicAdd(&part[P_EDGE + (blockIdx.x & 63) * 16], contrib);
}

// ---- dominant: MFMA bf16 upper-tri z@z^T + fused softplus ----------------
// XOR-swizzled unpadded LDS: tile = 128 rows x 8 int4 (BK=64), chunk ch of
// row r stored at slot ch^(r&7). 2 tiles x 16 KB = 32 KB -> higher occupancy.
__global__ __launch_bounds__(256, 3)
void tile_kernel(const unsigned short* __restrict__ zb, float* __restrict__ part) {
    const int bi = blockIdx.y, bj = blockIdx.x;
    if (bj < bi) return;   // upper triangle of 128x128 tiles

    __shared__ int4 la[128 * 8];
    __shared__ int4 lb[128 * 8];

    const int tid = threadIdx.x;
    const int wid = tid >> 6, lane = tid & 63;
    const int wm = wid >> 1, wn = wid & 1;
    const int l15 = lane & 15, quad = lane >> 4;
    const int xk = l15 & 7;                 // xor key for fragment reads

    const int4* ga = (const int4*)(zb + (size_t)bi * 128 * MM);
    const int4* gb = (const int4*)(zb + (size_t)bj * 128 * MM);

    f32x4 zero4 = {0.f, 0.f, 0.f, 0.f};
    f32x4 acc[4][4];
    #pragma unroll
    for (int i = 0; i < 4; ++i)
        #pragma unroll
        for (int j = 0; j < 4; ++j) acc[i][j] = zero4;

    const short* sa = (const short*)la;
    const short* sb = (const short*)lb;

    #pragma unroll
    for (int kc = 0; kc < 2; ++kc) {        // K halves of 64
        if (kc) __syncthreads();
        #pragma unroll
        for (int i = 0; i < 4; ++i) {       // stage both tiles, swizzled
            const int c = tid + i * 256;    // 0..1023
            const int row = c >> 3, ch = c & 7;
            const int sl = ch ^ (row & 7);
            la[row * 8 + sl] = ga[row * 16 + kc * 8 + ch];
            lb[row * 8 + sl] = gb[row * 16 + kc * 8 + ch];
        }
        __syncthreads();
        #pragma unroll
        for (int ks = 0; ks < 2; ++ks) {    // two k=32 MFMA steps
            const int kq = ks * 4 + quad;   // chunk index 0..7 (int4 units)
            bf16x8 af[4], bfr[4];
            #pragma unroll
            for (int t = 0; t < 4; ++t) {
                const int ar = wm * 64 + t * 16 + l15;
                af[t]  = *(const bf16x8*)&sa[ar * 64 + ((kq ^ xk) * 8)];
                const int br = wn * 64 + t * 16 + l15;
                bfr[t] = *(const bf16x8*)&sb[br * 64 + ((kq ^ xk) * 8)];
            }
            #pragma unroll
            for (int i = 0; i < 4; ++i)
                #pragma unroll
                for (int j = 0; j < 4; ++j)
                    acc[i][j] = __builtin_amdgcn_mfma_f32_16x16x32_bf16(
                        af[i], bfr[j], acc[i][j], 0, 0, 0);
        }
    }

    // softplus(v) ~= max(v,0) + e - e^2/2, e=exp(-|v|); err <= e^3/3,
    // summed bound ~1e5 << 1.2e7 threshold
    float tsum = 0.f;
    if (bi != bj) {
        #pragma unroll
        for (int i = 0; i < 4; ++i)
            #pragma unroll
            for (int j = 0; j < 4; ++j)
                #pragma unroll
                for (int r = 0; r < 4; ++r) {
                    const float v = acc[i][j][r];
                    const float e = __expf(-fabsf(v));
                    tsum += fmaxf(v, 0.f) + e * fmaf(e, -0.5f, 1.f);
                }
    } else {
        const int rbase = wm * 64 + quad * 4;
        const int cbase = wn * 64 + l15;
        #pragma unroll
        for (int i = 0; i < 4; ++i)
            #pragma unroll
            for (int j = 0; j < 4; ++j)
                #pragma unroll
                for (int r = 0; r < 4; ++r)
                    if (cbase + j * 16 > rbase + i * 16 + r) {
                        const float v = acc[i][j][r];
                        const float e = __expf(-fabsf(v));
                        tsum += fmaxf(v, 0.f) + e * fmaf(e, -0.5f, 1.f);
                    }
    }

    tsum = wave_reduce(tsum);
    if (lane == 0)   // per-wave atomic: no final barrier needed
        atomicAdd(&part[P_SP + ((bi * 64 + bj + wid * 16) & 63) * 16], tsum);
}

// ---- final combine: sum 3 x 64 partial slots ----------------------------
__global__ void combine_kernel(const float* __restrict__ part,
                               float* __restrict__ out) {
    const int t = threadIdx.x;   // 64 threads
    float v = part[P_SP + t * 16] - part[P_EDGE + t * 16]
            + 0.001f * part[P_KL + t * 16];
    v = wave_reduce(v);
    if (t == 0) out[0] = v;
}

extern "C" void kernel_launch(void* const* d_in, const int* in_sizes, int n_in,
                              void* d_out, int out_size, void* d_ws, size_t ws_size,
                              hipStream_t stream) {
    const float* x   = (const float*)d_in[0];
    const int* ei    = (const int*)d_in[1];     // int32 on device
    const float* eps = (const float*)d_in[2];
    const float* Wmu = (const float*)d_in[3];
    const float* bmu = (const float*)d_in[4];
    const float* Wsg = (const float*)d_in[5];
    const float* bsg = (const float*)d_in[6];
    float* out = (float*)d_out;
    char* ws = (char*)d_ws;

    float* part = (float*)ws;
    unsigned short* zb = (unsigned short*)(ws + Z_OFF);
    unsigned int* ht = (unsigned int*)(ws + HASH_OFF);
    unsigned short* WmuT = (unsigned short*)(ws + WT_OFF);
    unsigned short* WsgT = (unsigned short*)(ws + WT_OFF + WT_BYTES);
    const int E = in_sizes[1] / 2;

    prep_w<<<128, 256, 0, stream>>>(Wmu, Wsg, WmuT, WsgT, part, ht);
    encoder_mfma<<<NN / 16, 256, 0, stream>>>(x, eps, WmuT, WsgT, bmu, bsg, zb, part);
    edge_kernel<<<(E + 255) / 256, 256, 0, stream>>>(ei, E, zb, ht, part);
    dim3 grid(NN / 128, NN / 128);
    tile_kernel<<<grid, 256, 0, stream>>>(zb, part);
    combine_kernel<<<1, 64, 0, stream>>>(part, out);
}